// Round 19
// baseline (166.611 us; speedup 1.0000x reference)
//
#include <hip/hip_runtime.h>
#include <hip/hip_bf16.h>

#define BB 4
#define TT 4096
#define HH 2048
#define NSLOT 64
#define KD 256
#define VD 256
#define BT (BB*TT)
#define NEGV (-1e9f)
#define EPSV 1e-5f

typedef __attribute__((ext_vector_type(8))) short short8;
typedef __attribute__((ext_vector_type(4))) float floatx4;

union B8 { short8 v; unsigned short u[8]; };

__device__ inline unsigned short f2bf(float x) {
  unsigned u = __float_as_uint(x);
  return (unsigned short)((u + 0x7FFFu + ((u >> 16) & 1u)) >> 16);
}
__device__ inline float bf2f(unsigned short h) {
  return __uint_as_float(((unsigned)h) << 16);
}
__device__ inline void cvt8(const float4 a, const float4 b, B8& h, B8& l) {
  const float f[8] = {a.x, a.y, a.z, a.w, b.x, b.y, b.z, b.w};
#pragma unroll
  for (int j = 0; j < 8; ++j) {
    unsigned short hh = f2bf(f[j]);
    h.u[j] = hh;
    l.u[j] = f2bf(f[j] - bf2f(hh));
  }
}

// ---- prep_masks: mode detect + valid decode + ATOMIC compaction ------------
// tokList stores GLOBAL token ids. Slot order nondeterministic but per-token
// results are placement-independent -> output deterministic.
__global__ __launch_bounds__(256) void prep_masks_kernel(
    const void* valid_raw, const void* hist_raw,
    int* valid_int, int* tokList, int* nAllowed) {
  const int b = blockIdx.x;
  const int tid = threadIdx.x;
  __shared__ int mode_s;
  if (tid == 0) {
    const unsigned* u = (const unsigned*)valid_raw;
    int all01 = 1, anyf = 0;
    for (int i = 0; i < 64; ++i) {
      unsigned x = u[i];
      if (x != 0u && x != 1u) all01 = 0;
      if (x == 0x3F800000u) anyf = 1;
    }
    mode_s = all01 ? 0 : (anyf ? 1 : 2);
  }
  __syncthreads();
  const int mode = mode_s;
  const int* vi = (const int*)valid_raw;
  const float* vf = (const float*)valid_raw;
  const unsigned char* vb = (const unsigned char*)valid_raw;
  const int* hi = (const int*)hist_raw;
  const float* hf = (const float*)hist_raw;
  const unsigned char* hb = (const unsigned char*)hist_raw;

  if (tid < 64) {
    const int i = b * 64 + tid;
    valid_int[i] = (mode == 0) ? (vi[i] != 0)
                 : (mode == 1) ? (vf[i] != 0.0f)
                               : (vb[i] != 0);
  }

  for (int it = 0; it < 16; ++it) {
    const int t = it * 256 + tid;
    const int g = b * 4096 + t;
    const int masked = (mode == 0) ? (hi[g] != 0)
                     : (mode == 1) ? (hf[g] != 0.0f)
                                   : (hb[g] != 0);
    if (!masked) {
      const int slot = atomicAdd(&nAllowed[b], 1);
      tokList[b * 4096 + slot] = g;
    }
  }
}

// ---- merged prep: blk<128 -> PK frags (hi/lo), blk>=128 -> VW frags --------
__global__ __launch_bounds__(256) void prep_frags_kernel(
    const float* __restrict__ keys, const float* __restrict__ Wq,
    const float* __restrict__ vals, const float* __restrict__ Wo,
    unsigned short* __restrict__ PKh, unsigned short* __restrict__ PKl,
    unsigned short* __restrict__ VWTf) {
  __shared__ float bufA[64][260];
  __shared__ float bufB[64][261];
  const int tid = threadIdx.x;
  if (blockIdx.x < 128) {
    const int b = blockIdx.x >> 5;
    const int h0 = (blockIdx.x & 31) * 64;
    const float* kb = keys + (size_t)b * 64 * 256;
    for (int i = tid; i < 64 * 64; i += 256) {
      const int n = i >> 6, k4 = (i & 63) * 4;
      *(float4*)&bufA[n][k4] = *(const float4*)&kb[n * 256 + k4];
    }
    __syncthreads();
    const int h = h0 + (tid & 63);
    const int ng = tid >> 6;
    float acc[16] = {};
    for (int k = 0; k < 256; ++k) {
      const float wq = Wq[(size_t)k * HH + h];
#pragma unroll
      for (int i = 0; i < 16; ++i) acc[i] += bufA[i * 4 + ng][k] * wq;
    }
    const int kc = h >> 5, hk = (h >> 3) & 3, j = h & 7;
#pragma unroll
    for (int i = 0; i < 16; ++i) {
      const int n = i * 4 + ng;
      const int nt = n >> 4, frn = n & 15;
      const size_t idx =
          (((size_t)(b * 64 + kc) * 4 + nt) * 64 + hk * 16 + frn) * 8 + j;
      const unsigned short hh = f2bf(acc[i]);
      PKh[idx] = hh;
      PKl[idx] = f2bf(acc[i] - bf2f(hh));
    }
  } else {
    const int q = blockIdx.x - 128;
    const int b = q >> 5;
    const int h0 = (q & 31) * 64;
    const float* vbp = vals + (size_t)b * 64 * 256;
    for (int i = tid; i < 64 * 64; i += 256) {
      const int r = i >> 6, c4 = (i & 63) * 4;
      *(float4*)&bufA[r][c4] = *(const float4*)&vbp[r * 256 + c4];
      *(float4*)&bufB[r][c4] = *(const float4*)&Wo[(size_t)(h0 + r) * 256 + c4];
    }
    __syncthreads();
    const int hloc = tid & 63;
    const int ng = tid >> 6;
    const int h = h0 + hloc;
    float acc[16] = {};
    for (int v = 0; v < 256; ++v) {
      const float wo = bufB[hloc][v];
#pragma unroll
      for (int i = 0; i < 16; ++i) acc[i] += bufA[i * 4 + ng][v] * wo;
    }
    const int ht = h >> 4, fr = h & 15;
#pragma unroll
    for (int i = 0; i < 16; ++i) {
      const int n = i * 4 + ng;
      const int ks = n >> 5, hi4 = (n >> 3) & 3, j = n & 7;
      VWTf[(size_t)b * 131072 + (size_t)(ht * 2 + ks) * 512 +
           (hi4 * 16 + fr) * 8 + j] = f2bf(acc[i]);
    }
  }
}

// -------- attn v18: compacted GLOBAL tokens, direct frag-order loads --------
__global__ __launch_bounds__(256, 3) void attn_kernel(
    const float* __restrict__ hs,
    const unsigned short* __restrict__ PKh,
    const unsigned short* __restrict__ PKl,
    const int* __restrict__ valid,
    const int* __restrict__ tokList,
    const int* __restrict__ nAllowed,
    unsigned short* __restrict__ PB) {   // [BT][64] bf16, pre-zeroed
  const int b = blockIdx.x >> 8;
  const int t0l = (blockIdx.x & 255) * 16;
  const int nb = nAllowed[b];
  if (t0l >= nb) return;
  const int tid = threadIdx.x;
  const int w = tid >> 6, lane = tid & 63;
  const int fr = lane & 15, hi4 = lane >> 4;

  __shared__ float S[4][16][68];

  floatx4 aA[4], aB[4], aC[4];
#pragma unroll
  for (int nt = 0; nt < 4; ++nt) {
    aA[nt] = (floatx4){0.f, 0.f, 0.f, 0.f};
    aB[nt] = aA[nt];
    aC[nt] = aA[nt];
  }

  const int myPos = t0l + fr;
  const int myTok = tokList[b * 4096 + (myPos < nb ? myPos : nb - 1)];
  const float* gsrc = &hs[(size_t)myTok * HH + w * 512 + hi4 * 8];

  float4 va0[2], va1[2];
  va0[0] = *(const float4*)gsrc;
  va1[0] = *(const float4*)(gsrc + 4);
  va0[1] = *(const float4*)(gsrc + 32);
  va1[1] = *(const float4*)(gsrc + 36);

  short8 bhc[4], blc[4];
#pragma unroll
  for (int nt = 0; nt < 4; ++nt) {
    const size_t off = ((size_t)(b * 64 + w * 16) * 4 + nt) * 512 + lane * 8;
    bhc[nt] = *(const short8*)&PKh[off];
    blc[nt] = *(const short8*)&PKl[off];
  }

#pragma unroll 2
  for (int s = 0; s < 16; ++s) {
    const int rb = s & 1;
    B8 ah, al;
    cvt8(va0[rb], va1[rb], ah, al);
    if (s < 14) {
      va0[rb] = *(const float4*)(gsrc + (s + 2) * 32);
      va1[rb] = *(const float4*)(gsrc + (s + 2) * 32 + 4);
    }
#pragma unroll
    for (int nt = 0; nt < 4; ++nt) {
      aA[nt] = __builtin_amdgcn_mfma_f32_16x16x32_bf16(ah.v, bhc[nt], aA[nt], 0, 0, 0);
      aB[nt] = __builtin_amdgcn_mfma_f32_16x16x32_bf16(al.v, bhc[nt], aB[nt], 0, 0, 0);
      aC[nt] = __builtin_amdgcn_mfma_f32_16x16x32_bf16(ah.v, blc[nt], aC[nt], 0, 0, 0);
      if (s < 15) {
        const size_t off =
            ((size_t)(b * 64 + w * 16 + s + 1) * 4 + nt) * 512 + lane * 8;
        bhc[nt] = *(const short8*)&PKh[off];
        blc[nt] = *(const short8*)&PKl[off];
      }
    }
  }

#pragma unroll
  for (int nt = 0; nt < 4; ++nt) {
    const floatx4 acc = aA[nt] + aB[nt] + aC[nt];
#pragma unroll
    for (int rr = 0; rr < 4; ++rr)
      S[w][hi4 * 4 + rr][nt * 16 + fr] = acc[rr];
  }
  __syncthreads();

  const int vmy = valid[b * 64 + lane];
  const unsigned long long bal = __ballot(vmy != 0);
  const float any = (bal != 0ull) ? 1.0f : 0.0f;
#pragma unroll
  for (int i = 0; i < 4; ++i) {
    const int tt = w * 4 + i;
    const int pos = t0l + tt;
    float sv = S[0][tt][lane] + S[1][tt][lane] + S[2][tt][lane] + S[3][tt][lane];
    sv = vmy ? sv : NEGV;
    float m = sv;
#pragma unroll
    for (int o = 32; o; o >>= 1) m = fmaxf(m, __shfl_xor(m, o));
    const float e = __expf(sv - m);
    float sum = e;
#pragma unroll
    for (int o = 32; o; o >>= 1) sum += __shfl_xor(sum, o);
    if (pos < nb) {
      const int tok = tokList[b * 4096 + pos];
      PB[(size_t)tok * 64 + lane] = f2bf(e / sum * any);
    }
  }
}

// -------- fused output v2: out = LN(hs + (VW·P^T)^T), float4 epilogue -------
// Operand swap: A = VW frags (h rows -> M), B = P frags (tokens -> N).
// C layout: col(lane&15) = token, row(hi4*4+rr) = h  -> each lane holds 4
// CONSECUTIVE h values per acc -> float4 RES/gamma/beta/out accesses.
__global__ __launch_bounds__(512) void fuse_mfma_kernel(
    const unsigned short* __restrict__ PB,
    const unsigned short* __restrict__ VWTf,
    const float* __restrict__ RES,
    const float* __restrict__ gamma,
    const float* __restrict__ beta,
    float* __restrict__ out) {
  const int tok0 = blockIdx.x * 16;
  const int b = tok0 >> 12;
  const int tid = threadIdx.x;
  const int w = tid >> 6, lane = tid & 63;
  const int fr = lane & 15, hi4 = lane >> 4;

  __shared__ float part[16][8][2];
  __shared__ float stats[16][2];

  // B operand: P rows (tokens)
  const short8 pf0 = *(const short8*)&PB[(size_t)(tok0 + fr) * 64 + hi4 * 8];
  const short8 pf1 = *(const short8*)&PB[(size_t)(tok0 + fr) * 64 + 32 + hi4 * 8];

  floatx4 acc[16];
#pragma unroll
  for (int j = 0; j < 16; ++j) acc[j] = (floatx4){0.f, 0.f, 0.f, 0.f};

  const unsigned short* vbase =
      &VWTf[(size_t)b * 131072 + (size_t)(w * 16) * 2 * 512 + lane * 8];

  short8 br0[4], br1[4];
#pragma unroll
  for (int p = 0; p < 4; ++p) {
    br0[p] = *(const short8*)&vbase[(size_t)(p * 2 + 0) * 512];
    br1[p] = *(const short8*)&vbase[(size_t)(p * 2 + 1) * 512];
  }
#pragma unroll
  for (int ht = 0; ht < 16; ++ht) {
    const int cc = ht & 3;
    acc[ht] = __builtin_amdgcn_mfma_f32_16x16x32_bf16(br0[cc], pf0, acc[ht], 0, 0, 0);
    acc[ht] = __builtin_amdgcn_mfma_f32_16x16x32_bf16(br1[cc], pf1, acc[ht], 0, 0, 0);
    if (ht < 12) {
      br0[cc] = *(const short8*)&vbase[(size_t)((ht + 4) * 2 + 0) * 512];
      br1[cc] = *(const short8*)&vbase[(size_t)((ht + 4) * 2 + 1) * 512];
    }
  }

  // residual (float4) + per-token stats
  const int myTok = tok0 + fr;
  float s = 0.f, q = 0.f;
#pragma unroll
  for (int ht = 0; ht < 16; ++ht) {
    const int col = w * 256 + ht * 16 + hi4 * 4;
    const float4 r4 = *(const float4*)&RES[(size_t)myTok * HH + col];
    acc[ht][0] += r4.x;
    acc[ht][1] += r4.y;
    acc[ht][2] += r4.z;
    acc[ht][3] += r4.w;
#pragma unroll
    for (int rr = 0; rr < 4; ++rr) {
      s += acc[ht][rr];
      q += acc[ht][rr] * acc[ht][rr];
    }
  }
  // reduce over the 4 hi4 lane-groups holding the same token
  s += __shfl_xor(s, 16); q += __shfl_xor(q, 16);
  s += __shfl_xor(s, 32); q += __shfl_xor(q, 32);
  if (hi4 == 0) {
    part[fr][w][0] = s;
    part[fr][w][1] = q;
  }
  __syncthreads();
  if (tid < 16) {
    float Sm = 0.f, Q = 0.f;
#pragma unroll
    for (int ww = 0; ww < 8; ++ww) {
      Sm += part[tid][ww][0];
      Q += part[tid][ww][1];
    }
    const float mu = Sm * (1.0f / HH);
    const float var = Q * (1.0f / HH) - mu * mu;
    stats[tid][0] = mu;
    stats[tid][1] = rsqrtf(var + EPSV);
  }
  __syncthreads();

  const float mu = stats[fr][0], inv = stats[fr][1];
#pragma unroll
  for (int ht = 0; ht < 16; ++ht) {
    const int col = w * 256 + ht * 16 + hi4 * 4;
    const float4 g4 = *(const float4*)&gamma[col];
    const float4 b4 = *(const float4*)&beta[col];
    float4 o4;
    o4.x = (acc[ht][0] - mu) * inv * g4.x + b4.x;
    o4.y = (acc[ht][1] - mu) * inv * g4.y + b4.y;
    o4.z = (acc[ht][2] - mu) * inv * g4.z + b4.z;
    o4.w = (acc[ht][3] - mu) * inv * g4.w + b4.w;
    *(float4*)&out[(size_t)myTok * HH + col] = o4;
  }
}

extern "C" void kernel_launch(void* const* d_in, const int* in_sizes, int n_in,
                              void* d_out, int out_size, void* d_ws, size_t ws_size,
                              hipStream_t stream) {
  const float* hs    = (const float*)d_in[0];
  const float* keys  = (const float*)d_in[1];
  const float* vals  = (const float*)d_in[2];
  const float* Wq    = (const float*)d_in[3];
  const float* Wo    = (const float*)d_in[4];
  const float* gamma = (const float*)d_in[5];
  const float* beta  = (const float*)d_in[6];
  const void* valid_raw = d_in[7];
  const void* hist_raw  = d_in[8];
  float* out = (float*)d_out;

  char* w = (char*)d_ws;
  unsigned short* PKh  = (unsigned short*)w;                  // 1 MB
  unsigned short* PKl  = (unsigned short*)(w + (1u << 20));   // 1 MB
  unsigned short* VWTf = (unsigned short*)(w + (2u << 20));   // 1 MB
  unsigned short* PB   = (unsigned short*)(w + (3u << 20));   // 2 MB
  int* nAllowed  = (int*)(w + (5u << 20));                    // 16 B
  int* valid_int = (int*)(w + (5u << 20) + 1024);             // 1 KB
  int* tokList   = (int*)(w + (5u << 20) + 8192);             // 64 KB

  hipMemsetAsync(PB, 0, (size_t)BT * 64 * 2, stream);
  hipMemsetAsync(nAllowed, 0, 4 * sizeof(int), stream);
  prep_masks_kernel<<<dim3(4), dim3(256), 0, stream>>>(
      valid_raw, hist_raw, valid_int, tokList, nAllowed);
  prep_frags_kernel<<<dim3(256), dim3(256), 0, stream>>>(
      keys, Wq, vals, Wo, PKh, PKl, VWTf);
  attn_kernel<<<dim3(1024), dim3(256), 0, stream>>>(
      hs, PKh, PKl, valid_int, tokList, nAllowed, PB);
  fuse_mfma_kernel<<<dim3(BT / 16), dim3(512), 0, stream>>>(
      PB, VWTf, hs, gamma, beta, out);
}

// Round 20
// 133.631 us; speedup vs baseline: 1.2468x; 1.2468x over previous
//
#include <hip/hip_runtime.h>
#include <hip/hip_bf16.h>

#define BB 4
#define TT 4096
#define HH 2048
#define NSLOT 64
#define KD 256
#define VD 256
#define BT (BB*TT)
#define NEGV (-1e9f)
#define EPSV 1e-5f

typedef __attribute__((ext_vector_type(8))) short short8;
typedef __attribute__((ext_vector_type(4))) float floatx4;

union B8 { short8 v; unsigned short u[8]; };

__device__ inline unsigned short f2bf(float x) {
  unsigned u = __float_as_uint(x);
  return (unsigned short)((u + 0x7FFFu + ((u >> 16) & 1u)) >> 16);
}
__device__ inline float bf2f(unsigned short h) {
  return __uint_as_float(((unsigned)h) << 16);
}
__device__ inline void cvt8(const float4 a, const float4 b, B8& h, B8& l) {
  const float f[8] = {a.x, a.y, a.z, a.w, b.x, b.y, b.z, b.w};
#pragma unroll
  for (int j = 0; j < 8; ++j) {
    unsigned short hh = f2bf(f[j]);
    h.u[j] = hh;
    l.u[j] = f2bf(f[j] - bf2f(hh));
  }
}

// ---- mega_prep: one launch replaces masks + memsets + PK/VW frag prep ------
// blocks 0..3    : batch b mask decode + atomic compaction + PB zero (masked)
//                  (block zeroes its own nAllowed[b]; it is the sole producer)
// blocks 4..131  : PK = keys·Wq -> hi/lo bf16 frag layout
// blocks 132..259: VW = vals·Wo^T -> bf16 B-frag layout
__global__ __launch_bounds__(256) void mega_prep_kernel(
    const void* valid_raw, const void* hist_raw,
    const float* __restrict__ keys, const float* __restrict__ Wq,
    const float* __restrict__ vals, const float* __restrict__ Wo,
    int* valid_int, int* tokList, int* nAllowed,
    unsigned short* __restrict__ PKh, unsigned short* __restrict__ PKl,
    unsigned short* __restrict__ VWTf,
    unsigned short* __restrict__ PB) {
  __shared__ float bufA[64][260];
  __shared__ float bufB[64][261];
  const int tid = threadIdx.x;
  const int blk = blockIdx.x;

  if (blk < 4) {
    const int b = blk;
    __shared__ int mode_s;
    if (tid == 0) {
      nAllowed[b] = 0;
      const unsigned* u = (const unsigned*)valid_raw;
      int all01 = 1, anyf = 0;
      for (int i = 0; i < 64; ++i) {
        unsigned x = u[i];
        if (x != 0u && x != 1u) all01 = 0;
        if (x == 0x3F800000u) anyf = 1;
      }
      mode_s = all01 ? 0 : (anyf ? 1 : 2);
    }
    __syncthreads();
    const int mode = mode_s;
    const int* vi = (const int*)valid_raw;
    const float* vf = (const float*)valid_raw;
    const unsigned char* vb = (const unsigned char*)valid_raw;
    const int* hi = (const int*)hist_raw;
    const float* hf = (const float*)hist_raw;
    const unsigned char* hb = (const unsigned char*)hist_raw;

    if (tid < 64) {
      const int i = b * 64 + tid;
      valid_int[i] = (mode == 0) ? (vi[i] != 0)
                   : (mode == 1) ? (vf[i] != 0.0f)
                                 : (vb[i] != 0);
    }

    const short8 z8 = {0, 0, 0, 0, 0, 0, 0, 0};
    for (int it = 0; it < 16; ++it) {
      const int t = it * 256 + tid;
      const int g = b * 4096 + t;            // GLOBAL token id
      const int masked = (mode == 0) ? (hi[g] != 0)
                       : (mode == 1) ? (hf[g] != 0.0f)
                                     : (hb[g] != 0);
      if (!masked) {
        const int slot = atomicAdd(&nAllowed[b], 1);
        tokList[b * 4096 + slot] = g;
      } else {
        // zero this token's P row (64 bf16 = 8 x short8)
        unsigned short* p = &PB[(size_t)g * 64];
#pragma unroll
        for (int c = 0; c < 8; ++c) *(short8*)&p[c * 8] = z8;
      }
    }
  } else if (blk < 132) {
    const int q = blk - 4;
    const int b = q >> 5;
    const int h0 = (q & 31) * 64;
    const float* kb = keys + (size_t)b * 64 * 256;
    for (int i = tid; i < 64 * 64; i += 256) {
      const int n = i >> 6, k4 = (i & 63) * 4;
      *(float4*)&bufA[n][k4] = *(const float4*)&kb[n * 256 + k4];
    }
    __syncthreads();
    const int h = h0 + (tid & 63);
    const int ng = tid >> 6;
    float acc[16] = {};
    for (int k = 0; k < 256; ++k) {
      const float wq = Wq[(size_t)k * HH + h];
#pragma unroll
      for (int i = 0; i < 16; ++i) acc[i] += bufA[i * 4 + ng][k] * wq;
    }
    const int kc = h >> 5, hk = (h >> 3) & 3, j = h & 7;
#pragma unroll
    for (int i = 0; i < 16; ++i) {
      const int n = i * 4 + ng;
      const int nt = n >> 4, frn = n & 15;
      const size_t idx =
          (((size_t)(b * 64 + kc) * 4 + nt) * 64 + hk * 16 + frn) * 8 + j;
      const unsigned short hh = f2bf(acc[i]);
      PKh[idx] = hh;
      PKl[idx] = f2bf(acc[i] - bf2f(hh));
    }
  } else {
    const int q = blk - 132;
    const int b = q >> 5;
    const int h0 = (q & 31) * 64;
    const float* vbp = vals + (size_t)b * 64 * 256;
    for (int i = tid; i < 64 * 64; i += 256) {
      const int r = i >> 6, c4 = (i & 63) * 4;
      *(float4*)&bufA[r][c4] = *(const float4*)&vbp[r * 256 + c4];
      *(float4*)&bufB[r][c4] = *(const float4*)&Wo[(size_t)(h0 + r) * 256 + c4];
    }
    __syncthreads();
    const int hloc = tid & 63;
    const int ng = tid >> 6;
    const int h = h0 + hloc;
    float acc[16] = {};
    for (int v = 0; v < 256; ++v) {
      const float wo = bufB[hloc][v];
#pragma unroll
      for (int i = 0; i < 16; ++i) acc[i] += bufA[i * 4 + ng][v] * wo;
    }
    const int ht = h >> 4, fr = h & 15;
#pragma unroll
    for (int i = 0; i < 16; ++i) {
      const int n = i * 4 + ng;
      const int ks = n >> 5, hi4 = (n >> 3) & 3, j = n & 7;
      VWTf[(size_t)b * 131072 + (size_t)(ht * 2 + ks) * 512 +
           (hi4 * 16 + fr) * 8 + j] = f2bf(acc[i]);
    }
  }
}

// -------- attn v18: compacted GLOBAL tokens, direct frag-order loads --------
__global__ __launch_bounds__(256, 3) void attn_kernel(
    const float* __restrict__ hs,
    const unsigned short* __restrict__ PKh,
    const unsigned short* __restrict__ PKl,
    const int* __restrict__ valid,
    const int* __restrict__ tokList,
    const int* __restrict__ nAllowed,
    unsigned short* __restrict__ PB) {   // [BT][64] bf16 (masked rows zeroed)
  const int b = blockIdx.x >> 8;
  const int t0l = (blockIdx.x & 255) * 16;
  const int nb = nAllowed[b];
  if (t0l >= nb) return;
  const int tid = threadIdx.x;
  const int w = tid >> 6, lane = tid & 63;
  const int fr = lane & 15, hi4 = lane >> 4;

  __shared__ float S[4][16][68];

  floatx4 aA[4], aB[4], aC[4];
#pragma unroll
  for (int nt = 0; nt < 4; ++nt) {
    aA[nt] = (floatx4){0.f, 0.f, 0.f, 0.f};
    aB[nt] = aA[nt];
    aC[nt] = aA[nt];
  }

  const int myPos = t0l + fr;
  const int myTok = tokList[b * 4096 + (myPos < nb ? myPos : nb - 1)];  // GLOBAL
  const float* gsrc = &hs[(size_t)myTok * HH + w * 512 + hi4 * 8];

  float4 va0[2], va1[2];
  va0[0] = *(const float4*)gsrc;
  va1[0] = *(const float4*)(gsrc + 4);
  va0[1] = *(const float4*)(gsrc + 32);
  va1[1] = *(const float4*)(gsrc + 36);

  short8 bhc[4], blc[4];
#pragma unroll
  for (int nt = 0; nt < 4; ++nt) {
    const size_t off = ((size_t)(b * 64 + w * 16) * 4 + nt) * 512 + lane * 8;
    bhc[nt] = *(const short8*)&PKh[off];
    blc[nt] = *(const short8*)&PKl[off];
  }

#pragma unroll 2
  for (int s = 0; s < 16; ++s) {
    const int rb = s & 1;
    B8 ah, al;
    cvt8(va0[rb], va1[rb], ah, al);
    if (s < 14) {
      va0[rb] = *(const float4*)(gsrc + (s + 2) * 32);
      va1[rb] = *(const float4*)(gsrc + (s + 2) * 32 + 4);
    }
#pragma unroll
    for (int nt = 0; nt < 4; ++nt) {
      aA[nt] = __builtin_amdgcn_mfma_f32_16x16x32_bf16(ah.v, bhc[nt], aA[nt], 0, 0, 0);
      aB[nt] = __builtin_amdgcn_mfma_f32_16x16x32_bf16(al.v, bhc[nt], aB[nt], 0, 0, 0);
      aC[nt] = __builtin_amdgcn_mfma_f32_16x16x32_bf16(ah.v, blc[nt], aC[nt], 0, 0, 0);
      if (s < 15) {
        const size_t off =
            ((size_t)(b * 64 + w * 16 + s + 1) * 4 + nt) * 512 + lane * 8;
        bhc[nt] = *(const short8*)&PKh[off];
        blc[nt] = *(const short8*)&PKl[off];
      }
    }
  }

#pragma unroll
  for (int nt = 0; nt < 4; ++nt) {
    const floatx4 acc = aA[nt] + aB[nt] + aC[nt];
#pragma unroll
    for (int rr = 0; rr < 4; ++rr)
      S[w][hi4 * 4 + rr][nt * 16 + fr] = acc[rr];
  }
  __syncthreads();

  const int vmy = valid[b * 64 + lane];
  const unsigned long long bal = __ballot(vmy != 0);
  const float any = (bal != 0ull) ? 1.0f : 0.0f;
#pragma unroll
  for (int i = 0; i < 4; ++i) {
    const int tt = w * 4 + i;
    const int pos = t0l + tt;
    float sv = S[0][tt][lane] + S[1][tt][lane] + S[2][tt][lane] + S[3][tt][lane];
    sv = vmy ? sv : NEGV;
    float m = sv;
#pragma unroll
    for (int o = 32; o; o >>= 1) m = fmaxf(m, __shfl_xor(m, o));
    const float e = __expf(sv - m);
    float sum = e;
#pragma unroll
    for (int o = 32; o; o >>= 1) sum += __shfl_xor(sum, o);
    if (pos < nb) {
      const int tok = tokList[b * 4096 + pos];   // GLOBAL
      PB[(size_t)tok * 64 + lane] = f2bf(e / sum * any);
    }
  }
}

// -------- fused output via MFMA (r18-exact): out = LN(hs + P·VW^T) ----------
__global__ __launch_bounds__(512) void fuse_mfma_kernel(
    const unsigned short* __restrict__ PB,
    const unsigned short* __restrict__ VWTf,
    const float* __restrict__ RES,
    const float* __restrict__ gamma,
    const float* __restrict__ beta,
    float* __restrict__ out) {
  const int tok0 = blockIdx.x * 16;
  const int b = tok0 >> 12;
  const int tid = threadIdx.x;
  const int w = tid >> 6, lane = tid & 63;
  const int fr = lane & 15, hi4 = lane >> 4;

  __shared__ float part[16][8][2];
  __shared__ float stats[16][2];

  const short8 af0 = *(const short8*)&PB[(size_t)(tok0 + fr) * 64 + hi4 * 8];
  const short8 af1 = *(const short8*)&PB[(size_t)(tok0 + fr) * 64 + 32 + hi4 * 8];

  floatx4 acc[16];
#pragma unroll
  for (int j = 0; j < 16; ++j) acc[j] = (floatx4){0.f, 0.f, 0.f, 0.f};

  const unsigned short* vbase =
      &VWTf[(size_t)b * 131072 + (size_t)(w * 16) * 2 * 512 + lane * 8];

  short8 br0[4], br1[4];
#pragma unroll
  for (int p = 0; p < 4; ++p) {
    br0[p] = *(const short8*)&vbase[(size_t)(p * 2 + 0) * 512];
    br1[p] = *(const short8*)&vbase[(size_t)(p * 2 + 1) * 512];
  }
#pragma unroll
  for (int ht = 0; ht < 16; ++ht) {
    const int cc = ht & 3;
    acc[ht] = __builtin_amdgcn_mfma_f32_16x16x32_bf16(af0, br0[cc], acc[ht], 0, 0, 0);
    acc[ht] = __builtin_amdgcn_mfma_f32_16x16x32_bf16(af1, br1[cc], acc[ht], 0, 0, 0);
    if (ht < 12) {
      br0[cc] = *(const short8*)&vbase[(size_t)((ht + 4) * 2 + 0) * 512];
      br1[cc] = *(const short8*)&vbase[(size_t)((ht + 4) * 2 + 1) * 512];
    }
  }

  float s4[4] = {}, q4[4] = {};
#pragma unroll
  for (int ht = 0; ht < 16; ++ht) {
    const int col = w * 256 + ht * 16 + fr;
#pragma unroll
    for (int rr = 0; rr < 4; ++rr) {
      const int row = tok0 + hi4 * 4 + rr;
      const float x = acc[ht][rr] + RES[(size_t)row * HH + col];
      acc[ht][rr] = x;
      s4[rr] += x;
      q4[rr] += x * x;
    }
  }
#pragma unroll
  for (int rr = 0; rr < 4; ++rr) {
#pragma unroll
    for (int o = 1; o < 16; o <<= 1) {
      s4[rr] += __shfl_xor(s4[rr], o);
      q4[rr] += __shfl_xor(q4[rr], o);
    }
  }
  if (fr == 0) {
#pragma unroll
    for (int rr = 0; rr < 4; ++rr) {
      part[hi4 * 4 + rr][w][0] = s4[rr];
      part[hi4 * 4 + rr][w][1] = q4[rr];
    }
  }
  __syncthreads();
  if (tid < 16) {
    float Sm = 0.f, Q = 0.f;
#pragma unroll
    for (int ww = 0; ww < 8; ++ww) {
      Sm += part[tid][ww][0];
      Q += part[tid][ww][1];
    }
    const float mu = Sm * (1.0f / HH);
    const float var = Q * (1.0f / HH) - mu * mu;
    stats[tid][0] = mu;
    stats[tid][1] = rsqrtf(var + EPSV);
  }
  __syncthreads();

#pragma unroll
  for (int ht = 0; ht < 16; ++ht) {
    const int col = w * 256 + ht * 16 + fr;
    const float g = gamma[col], bb = beta[col];
#pragma unroll
    for (int rr = 0; rr < 4; ++rr) {
      const int row = hi4 * 4 + rr;
      out[(size_t)(tok0 + row) * HH + col] =
          (acc[ht][rr] - stats[row][0]) * stats[row][1] * g + bb;
    }
  }
}

extern "C" void kernel_launch(void* const* d_in, const int* in_sizes, int n_in,
                              void* d_out, int out_size, void* d_ws, size_t ws_size,
                              hipStream_t stream) {
  const float* hs    = (const float*)d_in[0];
  const float* keys  = (const float*)d_in[1];
  const float* vals  = (const float*)d_in[2];
  const float* Wq    = (const float*)d_in[3];
  const float* Wo    = (const float*)d_in[4];
  const float* gamma = (const float*)d_in[5];
  const float* beta  = (const float*)d_in[6];
  const void* valid_raw = d_in[7];
  const void* hist_raw  = d_in[8];
  float* out = (float*)d_out;

  char* w = (char*)d_ws;
  unsigned short* PKh  = (unsigned short*)w;                  // 1 MB
  unsigned short* PKl  = (unsigned short*)(w + (1u << 20));   // 1 MB
  unsigned short* VWTf = (unsigned short*)(w + (2u << 20));   // 1 MB
  unsigned short* PB   = (unsigned short*)(w + (3u << 20));   // 2 MB
  int* nAllowed  = (int*)(w + (5u << 20));                    // 16 B
  int* valid_int = (int*)(w + (5u << 20) + 1024);             // 1 KB
  int* tokList   = (int*)(w + (5u << 20) + 8192);             // 64 KB

  mega_prep_kernel<<<dim3(260), dim3(256), 0, stream>>>(
      valid_raw, hist_raw, keys, Wq, vals, Wo,
      valid_int, tokList, nAllowed, PKh, PKl, VWTf, PB);
  attn_kernel<<<dim3(1024), dim3(256), 0, stream>>>(
      hs, PKh, PKl, valid_int, tokList, nAllowed, PB);
  fuse_mfma_kernel<<<dim3(BT / 16), dim3(512), 0, stream>>>(
      PB, VWTf, hs, gamma, beta, out);
}